// Round 2
// baseline (217.577 us; speedup 1.0000x reference)
//
#include <hip/hip_runtime.h>
#include <math.h>

namespace {
constexpr int NIN   = 32;
constexpr int H_    = 14;
constexpr int CIN   = 8;
constexpr int C_    = 32;
constexpr int COUT  = 16;
constexpr int R_    = 288;
constexpr int W_    = 12;
constexpr int NITER = 3;
constexpr int CH    = 32;              // r per chunk
constexpr int NCH   = 9;               // 288/32
constexpr size_t XSUB = (size_t)NIN * H_ * H_ * CIN;   // x stride per batch elem
}

typedef unsigned int u32;
typedef const __attribute__((address_space(1))) u32* as1_u32p;
typedef __attribute__((address_space(3))) u32* as3_u32p;

__device__ __forceinline__ void async_copy16(const void* g, void* l) {
    __builtin_amdgcn_global_load_lds((as1_u32p)g, (as3_u32p)l, 16, 0, 0);
}
__device__ __forceinline__ float dot4(const float4 a, const float4 b) {
    return fmaf(a.x, b.x, fmaf(a.y, b.y, fmaf(a.z, b.z, a.w * b.w)));
}
// VALU-pipe cross-lane ops (DPP) — keep traffic off the DS pipe.
// quad_perm[a,b,c,d] ctrl = a|(b<<2)|(c<<4)|(d<<6); row_shr:N = 0x110|N.
__device__ __forceinline__ float dpp_add_xor1(float v) {
    int t = __builtin_amdgcn_update_dpp(0, __float_as_int(v), 0xB1, 0xF, 0xF, true);
    return v + __int_as_float(t);
}
__device__ __forceinline__ float dpp_add_xor2(float v) {
    int t = __builtin_amdgcn_update_dpp(0, __float_as_int(v), 0x4E, 0xF, 0xF, true);
    return v + __int_as_float(t);
}
__device__ __forceinline__ float dpp_add_shr4(float v) {
    int t = __builtin_amdgcn_update_dpp(0, __float_as_int(v), 0x114, 0xF, 0xF, true);
    return v + __int_as_float(t);
}
__device__ __forceinline__ float dpp_add_shr8(float v) {
    int t = __builtin_amdgcn_update_dpp(0, __float_as_int(v), 0x118, 0xF, 0xF, true);
    return v + __int_as_float(t);
}
template <int CTRL>
__device__ __forceinline__ float dpp_bc(float v) {   // quad broadcast (mov)
    return __int_as_float(
        __builtin_amdgcn_update_dpp(0, __float_as_int(v), CTRL, 0xF, 0xF, true));
}

// One block (256 thr) per (c, b-QUAD, p, q) — R12 compute skeleton.
// R14: priors loop rebuilt as a counted-vmcnt pipeline (T3/T4):
//   * 3 full-chunk W buffers (48 KB), stage distance 2 — each stage(k) has
//     ~2 compute phases (~500 cy) of latency cover before its wait.
//   * raw s_barrier + "s_waitcnt vmcnt(N)" with exact counted N; the
//     __syncthreads vmcnt(0) drain (which forced distance-1 cover, proven
//     latency-marginal by R13's regression) is gone from the main loop.
//   * xld(k+1) issued BEFORE stage(k+2) so the xv data-dep wait is
//     vmcnt(9) and never drains the in-flight stages.
//   * sched_barrier(0) after s_barrier pins ds_reads (rule 18).
// Race safety: stage(k+2) is issued after barrier(k), which certifies all
// waves finished compute(k-1) — the previous reader of buffer (k+2)%3.
// Each wave vmcnt-waits its own stage(k) before barrier(k), so post-
// barrier reads of buffer k%3 see completed writes from all waves.
// Lessons kept: 256-thr blocks (512 regressed: R6, R10); no forced
// waves/EU (R4 spill); staging via zero-VGPR global_load_lds (R7);
// priors fp32 (R2); cross-lane on DPP where possible (R9/R11);
// occupancy is VGPR-bucket-capped, not LDS-capped (R13).
__global__ __launch_bounds__(256)
void caps_routeC(const float* __restrict__ x,
                 const float* __restrict__ rw,
                 float* __restrict__ out)
{
    const int tid = threadIdx.x;
    const int p  = blockIdx.x / W_;
    const int q  = blockIdx.x % W_;
    const int b0 = blockIdx.y * 4;
    const int c  = blockIdx.z;

    __shared__ float4 wbuf[3][1024];   // [buf][i(8)][cr(32)][og(4)] 16 KB each
    __shared__ float  sRed[4][2][16];  // [wave][local sub][o]
    __shared__ float  redE[4][2];      // [wave][local sub]
    __shared__ float  vS[4][16];       // [sub][o]

    const int og   = tid & 3;
    const int rl   = tid >> 2;     // 0..63
    const int cr   = rl & 31;      // chunk-local r
    const int sh   = rl >> 5;      // wave-uniform: waves 0,1 -> subs 0,1; 2,3 -> 2,3
    const int lane = tid & 63;
    const int wv   = tid >> 6;
    const int sA   = sh * 2;       // first sub of this thread's pair

    // per-lane x base: lane og covers (sub sA + (og>>1), float4-half og&1)
    const float* xq = x + (size_t)(b0 + sA + (og >> 1)) * XSUB + (og & 1) * 4;
    const float4* rwcF4 = (const float4*)(rw + (size_t)c * R_ * CIN * COUT);

    float4 xvb[2];                 // double x-prefetch slots (static idx under unroll)
    auto xld = [&](int k, int slot) {
        const int r  = k * CH + cr;
        const int n  = r / 9, rem = r - n * 9;
        const int kh = rem / 3, kw = rem - kh * 3;
        xvb[slot] = *(const float4*)(xq + ((n * H_ + (p + kh)) * H_ + (q + kw)) * CIN);
    };

    auto stage = [&](int k, int buf) {
        // slot s = t*256+tid -> [ii=s>>7][wcr=(s>>2)&31][wog=s&3];
        // global f4 = wcr*32 + ii*4 + wog (chunk base k*1024 f4)
        const float4* gchunk = rwcF4 + (size_t)k * (CH * 32);
        #pragma unroll
        for (int t = 0; t < 4; ++t) {
            const int s   = t * 256 + tid;
            const int ii  = s >> 7;
            const int wcr = (s >> 2) & 31;
            async_copy16(gchunk + (wcr * 32 + ii * 4 + (s & 3)),
                         (char*)&wbuf[buf][0] + (t * 256 + (tid & 192)) * 16);
        }
    };

    float4 acc[NCH][2];

    xld(0, 0);
    stage(0, 0);
    stage(1, 1);
    #pragma unroll
    for (int k = 0; k < NCH; ++k) {
        // Wait own stage(k) landed; keep newer stages + x-loads in flight.
        // Outstanding (issue order) at this point:
        //   k=0:   stage(0):4, stage(1):4                     -> vmcnt(4)
        //   1<=k<=7: stage(k):4, xld(k):1?, ... newer = xld(k)+stage(k+1) = 5
        //   k=8:   stage(8):4, xld(8):1                        -> vmcnt(1)
        if (k == 0)            asm volatile("s_waitcnt vmcnt(4)" ::: "memory");
        else if (k == NCH - 1) asm volatile("s_waitcnt vmcnt(1)" ::: "memory");
        else                   asm volatile("s_waitcnt vmcnt(5)" ::: "memory");
        __builtin_amdgcn_s_barrier();
        __builtin_amdgcn_sched_barrier(0);
        if (k + 1 < NCH) xld(k + 1, (k + 1) & 1);     // before stage: xv dep-wait
        if (k + 2 < NCH) stage(k + 2, (k + 2) % 3);   //   then never drains stages
        // og-quad exchange: fA = sub sA floats 0..7, fB = sub sA+1 (VALU)
        const float4 cur = xvb[k & 1];
        float fA[8], fB[8];
        fA[0] = dpp_bc<0x00>(cur.x); fA[1] = dpp_bc<0x00>(cur.y);
        fA[2] = dpp_bc<0x00>(cur.z); fA[3] = dpp_bc<0x00>(cur.w);
        fA[4] = dpp_bc<0x55>(cur.x); fA[5] = dpp_bc<0x55>(cur.y);
        fA[6] = dpp_bc<0x55>(cur.z); fA[7] = dpp_bc<0x55>(cur.w);
        fB[0] = dpp_bc<0xAA>(cur.x); fB[1] = dpp_bc<0xAA>(cur.y);
        fB[2] = dpp_bc<0xAA>(cur.z); fB[3] = dpp_bc<0xAA>(cur.w);
        fB[4] = dpp_bc<0xFF>(cur.x); fB[5] = dpp_bc<0xFF>(cur.y);
        fB[6] = dpp_bc<0xFF>(cur.z); fB[7] = dpp_bc<0xFF>(cur.w);
        const float4* wb = &wbuf[k % 3][0];
        float4 a0 = make_float4(0.f, 0.f, 0.f, 0.f);
        float4 a1 = make_float4(0.f, 0.f, 0.f, 0.f);
        #pragma unroll
        for (int i = 0; i < 8; ++i) {
            const float4 wv4 = wb[i * 128 + cr * 4 + og];   // conflict-free b128
            a0.x = fmaf(fA[i], wv4.x, a0.x);  a1.x = fmaf(fB[i], wv4.x, a1.x);
            a0.y = fmaf(fA[i], wv4.y, a0.y);  a1.y = fmaf(fB[i], wv4.y, a1.y);
            a0.z = fmaf(fA[i], wv4.z, a0.z);  a1.z = fmaf(fB[i], wv4.z, a1.z);
            a0.w = fmaf(fA[i], wv4.w, a0.w);  a1.w = fmaf(fB[i], wv4.w, a1.w);
        }
        acc[k][0] = a0;  acc[k][1] = a1;
    }

    float lgA[NCH], lgB[NCH];
    #pragma unroll
    for (int j = 0; j < NCH; ++j) { lgA[j] = 0.f; lgB[j] = 0.f; }

    for (int it = 0; it < NITER; ++it) {
        float4 s0 = make_float4(0.f, 0.f, 0.f, 0.f);
        float4 s1 = make_float4(0.f, 0.f, 0.f, 0.f);
        float se0 = 0.f, se1 = 0.f;

        if (it == 0) {
            #pragma unroll
            for (int j = 0; j < NCH; ++j) {
                s0.x += acc[j][0].x;  s1.x += acc[j][1].x;
                s0.y += acc[j][0].y;  s1.y += acc[j][1].y;
                s0.z += acc[j][0].z;  s1.z += acc[j][1].z;
                s0.w += acc[j][0].w;  s1.w += acc[j][1].w;
            }
        } else {
            const float4 v0 = *(const float4*)&vS[sA][og * 4];
            const float4 v1 = *(const float4*)&vS[sA + 1][og * 4];
            #pragma unroll
            for (int j = 0; j < NCH; ++j) {
                float d0 = dot4(acc[j][0], v0);
                float d1 = dot4(acc[j][1], v1);
                d0 = dpp_add_xor1(d0);  d1 = dpp_add_xor1(d1);   // VALU
                d0 = dpp_add_xor2(d0);  d1 = dpp_add_xor2(d1);
                lgA[j] += d0;                 lgB[j] += d1;
                const float e0 = __expf(lgA[j]);
                const float e1 = __expf(lgB[j]);
                se0 += e0;                    se1 += e1;
                s0.x = fmaf(e0, acc[j][0].x, s0.x);  s1.x = fmaf(e1, acc[j][1].x, s1.x);
                s0.y = fmaf(e0, acc[j][0].y, s0.y);  s1.y = fmaf(e1, acc[j][1].y, s1.y);
                s0.z = fmaf(e0, acc[j][0].z, s0.z);  s1.z = fmaf(e1, acc[j][1].z, s1.z);
                s0.w = fmaf(e0, acc[j][0].w, s0.w);  s1.w = fmaf(e1, acc[j][1].w, s1.w);
            }
            // se: og-redundant; lane bits 2-3 on DPP, 4-5 on swizzle
            se0 = dpp_add_shr4(se0);  se1 = dpp_add_shr4(se1);
            se0 = dpp_add_shr8(se0);  se1 = dpp_add_shr8(se1);
            se0 += __shfl_xor(se0, 16, 64);  se1 += __shfl_xor(se1, 16, 64);
            se0 += __shfl_xor(se0, 32, 64);  se1 += __shfl_xor(se1, 32, 64);
            if (lane == 15) { redE[wv][0] = se0; redE[wv][1] = se1; }
        }

        // s-reduce over the wave's 16 cr-slots: bits 2-3 via DPP row_shr
        // (og-preserving; totals in lanes 12..15), bits 4-5 via swizzle.
        s0.x = dpp_add_shr4(s0.x);  s1.x = dpp_add_shr4(s1.x);
        s0.y = dpp_add_shr4(s0.y);  s1.y = dpp_add_shr4(s1.y);
        s0.z = dpp_add_shr4(s0.z);  s1.z = dpp_add_shr4(s1.z);
        s0.w = dpp_add_shr4(s0.w);  s1.w = dpp_add_shr4(s1.w);
        s0.x = dpp_add_shr8(s0.x);  s1.x = dpp_add_shr8(s1.x);
        s0.y = dpp_add_shr8(s0.y);  s1.y = dpp_add_shr8(s1.y);
        s0.z = dpp_add_shr8(s0.z);  s1.z = dpp_add_shr8(s1.z);
        s0.w = dpp_add_shr8(s0.w);  s1.w = dpp_add_shr8(s1.w);
        #pragma unroll
        for (int off = 16; off <= 32; off <<= 1) {
            s0.x += __shfl_xor(s0.x, off, 64);  s1.x += __shfl_xor(s1.x, off, 64);
            s0.y += __shfl_xor(s0.y, off, 64);  s1.y += __shfl_xor(s1.y, off, 64);
            s0.z += __shfl_xor(s0.z, off, 64);  s1.z += __shfl_xor(s1.z, off, 64);
            s0.w += __shfl_xor(s0.w, off, 64);  s1.w += __shfl_xor(s1.w, off, 64);
        }
        if (lane >= 12 && lane < 16) {   // lanes 12..15, og = lane&3
            *(float4*)&sRed[wv][0][(lane & 3) * 4] = s0;
            *(float4*)&sRed[wv][1][(lane & 3) * 4] = s1;
        }
        __syncthreads();

        // ---- squash: 64 threads = (sub 0..3, o 0..15)
        if (tid < 64) {
            const int sub = tid >> 4;
            const int o   = tid & 15;
            const int g   = sub >> 1;      // wave-pair group
            const int l   = sub & 1;       // local sub within pair
            const float inv = (it == 0)
                ? (1.0f / (float)R_)
                : 1.0f / (redE[g * 2][l] + redE[g * 2 + 1][l]);
            float s = (sRed[g * 2][l][o] + sRed[g * 2 + 1][l][o]) * inv;
            float sn = s * s;
            sn = dpp_add_xor1(sn);
            sn = dpp_add_xor2(sn);
            sn += __shfl_xor(sn, 4, 64);
            sn += __shfl_xor(sn, 8, 64);
            const float v = s * (sqrtf(sn) / (1.0f + sn));
            if (it == NITER - 1) {
                out[((((size_t)(b0 + sub) * C_ + c) * W_ + p) * W_ + q) * COUT + o] = v;
            } else {
                vS[sub][o] = v;
            }
        }
        if (it == NITER - 1) break;
        __syncthreads();   // vS visible before next iteration
    }
}

extern "C" void kernel_launch(void* const* d_in, const int* in_sizes, int n_in,
                              void* d_out, int out_size, void* d_ws, size_t ws_size,
                              hipStream_t stream) {
    const float* x  = (const float*)d_in[0];
    const float* rw = (const float*)d_in[1];
    float* out = (float*)d_out;
    dim3 grid(W_ * W_, 2, C_);
    caps_routeC<<<grid, 256, 0, stream>>>(x, rw, out);
}

// Round 3
// 197.896 us; speedup vs baseline: 1.0994x; 1.0994x over previous
//
#include <hip/hip_runtime.h>
#include <math.h>

namespace {
constexpr int NIN   = 32;
constexpr int H_    = 14;
constexpr int CIN   = 8;
constexpr int C_    = 32;
constexpr int COUT  = 16;
constexpr int R_    = 288;
constexpr int W_    = 12;
constexpr int NITER = 3;
constexpr int CH    = 32;              // r per chunk
constexpr int NCH   = 9;               // 288/32
constexpr size_t XSUB = (size_t)NIN * H_ * H_ * CIN;   // x stride per batch elem
}

typedef unsigned int u32;
typedef const __attribute__((address_space(1))) u32* as1_u32p;
typedef __attribute__((address_space(3))) u32* as3_u32p;

__device__ __forceinline__ void async_copy16(const void* g, void* l) {
    __builtin_amdgcn_global_load_lds((as1_u32p)g, (as3_u32p)l, 16, 0, 0);
}
__device__ __forceinline__ float dot4(const float4 a, const float4 b) {
    return fmaf(a.x, b.x, fmaf(a.y, b.y, fmaf(a.z, b.z, a.w * b.w)));
}
// VALU-pipe cross-lane ops (DPP) — keep traffic off the DS pipe.
// quad_perm[a,b,c,d] ctrl = a|(b<<2)|(c<<4)|(d<<6); row_shr:N = 0x110|N.
__device__ __forceinline__ float dpp_add_xor1(float v) {
    int t = __builtin_amdgcn_update_dpp(0, __float_as_int(v), 0xB1, 0xF, 0xF, true);
    return v + __int_as_float(t);
}
__device__ __forceinline__ float dpp_add_xor2(float v) {
    int t = __builtin_amdgcn_update_dpp(0, __float_as_int(v), 0x4E, 0xF, 0xF, true);
    return v + __int_as_float(t);
}
__device__ __forceinline__ float dpp_add_shr4(float v) {
    int t = __builtin_amdgcn_update_dpp(0, __float_as_int(v), 0x114, 0xF, 0xF, true);
    return v + __int_as_float(t);
}
__device__ __forceinline__ float dpp_add_shr8(float v) {
    int t = __builtin_amdgcn_update_dpp(0, __float_as_int(v), 0x118, 0xF, 0xF, true);
    return v + __int_as_float(t);
}
template <int CTRL>
__device__ __forceinline__ float dpp_bc(float v) {   // quad broadcast (mov)
    return __int_as_float(
        __builtin_amdgcn_update_dpp(0, __float_as_int(v), CTRL, 0xF, 0xF, true));
}

// One block (256 thr) per (c, b-QUAD, p, q) — R12 priors skeleton (best).
// R15 changes (occupancy is pinned at ~10 waves/CU by the VGPR 128-granule —
// R13/R14 proved LDS/pipeline levers don't move it; attack per-block
// critical path instead):
//  (a) routing epilogue: all-wave redundant squash. After the in-wave
//      s-reduce, lanes 12..15 store partials; ONE barrier; then EVERY
//      thread reads both wave-partials of its sub-pair, sums, and computes
//      its own og-quad of the squash (sn via dot4 + quad-DPP xor1/xor2).
//      v0/v1 live in registers across iterations. Deletes the 64-thread
//      divergent phase, the vS round-trip, and 2 of 5 routing barriers.
//      sRed/redE double-buffered by iteration parity (race safety).
//  (b) x gather prefetch distance 2 (xvb[2]): the 32-segment xld gather
//      partially misses to L3/HBM (600-900 cy); distance-1 (~400 cy) was
//      marginal cover. +4 VGPRs, same 128 bucket.
// Lessons kept: 256-thr blocks (R6/R10); no forced waves/EU (R4); staging
// via zero-VGPR global_load_lds + plain __syncthreads (R7, R14-revert);
// priors fp32 (R2); cross-lane on DPP (R9/R11); LDS<40K is occupancy-free,
// VGPR bucket is the cap (R13/R14).
__global__ __launch_bounds__(256)
void caps_routeC(const float* __restrict__ x,
                 const float* __restrict__ rw,
                 float* __restrict__ out)
{
    const int tid = threadIdx.x;
    const int p  = blockIdx.x / W_;
    const int q  = blockIdx.x % W_;
    const int b0 = blockIdx.y * 4;
    const int c  = blockIdx.z;

    __shared__ float4 wbuf[2][1024];     // [buf][i(8)][cr(32)][og(4)] 16 KB each
    __shared__ float  sRed[2][4][2][16]; // [parity][wave][local sub][o]
    __shared__ float  redE[2][4][2];     // [parity][wave][local sub]

    const int og   = tid & 3;
    const int rl   = tid >> 2;     // 0..63
    const int cr   = rl & 31;      // chunk-local r
    const int sh   = rl >> 5;      // wave-uniform: waves 0,1 -> subs 0,1; 2,3 -> 2,3
    const int lane = tid & 63;
    const int wv   = tid >> 6;
    const int sA   = sh * 2;       // first sub of this thread's pair

    // per-lane x base: lane og covers (sub sA + (og>>1), float4-half og&1)
    const float* xq = x + (size_t)(b0 + sA + (og >> 1)) * XSUB + (og & 1) * 4;
    const float4* rwcF4 = (const float4*)(rw + (size_t)c * R_ * CIN * COUT);

    float4 xvb[2];                 // distance-2 x prefetch slots
    auto xld = [&](int k, int slot) {
        const int r  = k * CH + cr;
        const int n  = r / 9, rem = r - n * 9;
        const int kh = rem / 3, kw = rem - kh * 3;
        xvb[slot] = *(const float4*)(xq + ((n * H_ + (p + kh)) * H_ + (q + kw)) * CIN);
    };

    auto stage = [&](int k, int buf) {
        // slot s = t*256+tid -> [ii=s>>7][wcr=(s>>2)&31][wog=s&3];
        // global f4 = wcr*32 + ii*4 + wog (chunk base k*1024 f4)
        const float4* gchunk = rwcF4 + (size_t)k * (CH * 32);
        #pragma unroll
        for (int t = 0; t < 4; ++t) {
            const int s   = t * 256 + tid;
            const int ii  = s >> 7;
            const int wcr = (s >> 2) & 31;
            async_copy16(gchunk + (wcr * 32 + ii * 4 + (s & 3)),
                         (char*)&wbuf[buf][0] + (t * 256 + (tid & 192)) * 16);
        }
    };

    float4 acc[NCH][2];

    xld(0, 0);
    xld(1, 1);
    stage(0, 0);
    #pragma unroll
    for (int k = 0; k < NCH; ++k) {
        __syncthreads();               // stage(k) drained on all waves; other buf free
        if (k + 1 < NCH) stage(k + 1, (k + 1) & 1);
        // og-quad exchange: fA = sub sA floats 0..7, fB = sub sA+1 (VALU)
        const float4 cur = xvb[k & 1];
        float fA[8], fB[8];
        fA[0] = dpp_bc<0x00>(cur.x); fA[1] = dpp_bc<0x00>(cur.y);
        fA[2] = dpp_bc<0x00>(cur.z); fA[3] = dpp_bc<0x00>(cur.w);
        fA[4] = dpp_bc<0x55>(cur.x); fA[5] = dpp_bc<0x55>(cur.y);
        fA[6] = dpp_bc<0x55>(cur.z); fA[7] = dpp_bc<0x55>(cur.w);
        fB[0] = dpp_bc<0xAA>(cur.x); fB[1] = dpp_bc<0xAA>(cur.y);
        fB[2] = dpp_bc<0xAA>(cur.z); fB[3] = dpp_bc<0xAA>(cur.w);
        fB[4] = dpp_bc<0xFF>(cur.x); fB[5] = dpp_bc<0xFF>(cur.y);
        fB[6] = dpp_bc<0xFF>(cur.z); fB[7] = dpp_bc<0xFF>(cur.w);
        if (k + 2 < NCH) xld(k + 2, k & 1);   // slot freed (cur extracted)
        const float4* wb = &wbuf[k & 1][0];
        float4 a0 = make_float4(0.f, 0.f, 0.f, 0.f);
        float4 a1 = make_float4(0.f, 0.f, 0.f, 0.f);
        #pragma unroll
        for (int i = 0; i < 8; ++i) {
            const float4 wv4 = wb[i * 128 + cr * 4 + og];   // conflict-free b128
            a0.x = fmaf(fA[i], wv4.x, a0.x);  a1.x = fmaf(fB[i], wv4.x, a1.x);
            a0.y = fmaf(fA[i], wv4.y, a0.y);  a1.y = fmaf(fB[i], wv4.y, a1.y);
            a0.z = fmaf(fA[i], wv4.z, a0.z);  a1.z = fmaf(fB[i], wv4.z, a1.z);
            a0.w = fmaf(fA[i], wv4.w, a0.w);  a1.w = fmaf(fB[i], wv4.w, a1.w);
        }
        acc[k][0] = a0;  acc[k][1] = a1;
    }

    float lgA[NCH], lgB[NCH];
    #pragma unroll
    for (int j = 0; j < NCH; ++j) { lgA[j] = 0.f; lgB[j] = 0.f; }

    float4 v0, v1;   // squash output for subs sA, sA+1, couts og*4..og*4+3

    for (int it = 0; it < NITER; ++it) {
        const int par = it & 1;
        float4 s0 = make_float4(0.f, 0.f, 0.f, 0.f);
        float4 s1 = make_float4(0.f, 0.f, 0.f, 0.f);
        float se0 = 0.f, se1 = 0.f;

        if (it == 0) {
            #pragma unroll
            for (int j = 0; j < NCH; ++j) {
                s0.x += acc[j][0].x;  s1.x += acc[j][1].x;
                s0.y += acc[j][0].y;  s1.y += acc[j][1].y;
                s0.z += acc[j][0].z;  s1.z += acc[j][1].z;
                s0.w += acc[j][0].w;  s1.w += acc[j][1].w;
            }
        } else {
            #pragma unroll
            for (int j = 0; j < NCH; ++j) {
                float d0 = dot4(acc[j][0], v0);
                float d1 = dot4(acc[j][1], v1);
                d0 = dpp_add_xor1(d0);  d1 = dpp_add_xor1(d1);   // VALU
                d0 = dpp_add_xor2(d0);  d1 = dpp_add_xor2(d1);
                lgA[j] += d0;                 lgB[j] += d1;
                const float e0 = __expf(lgA[j]);
                const float e1 = __expf(lgB[j]);
                se0 += e0;                    se1 += e1;
                s0.x = fmaf(e0, acc[j][0].x, s0.x);  s1.x = fmaf(e1, acc[j][1].x, s1.x);
                s0.y = fmaf(e0, acc[j][0].y, s0.y);  s1.y = fmaf(e1, acc[j][1].y, s1.y);
                s0.z = fmaf(e0, acc[j][0].z, s0.z);  s1.z = fmaf(e1, acc[j][1].z, s1.z);
                s0.w = fmaf(e0, acc[j][0].w, s0.w);  s1.w = fmaf(e1, acc[j][1].w, s1.w);
            }
            // se: og-redundant; lane bits 2-3 on DPP, 4-5 on swizzle
            se0 = dpp_add_shr4(se0);  se1 = dpp_add_shr4(se1);
            se0 = dpp_add_shr8(se0);  se1 = dpp_add_shr8(se1);
            se0 += __shfl_xor(se0, 16, 64);  se1 += __shfl_xor(se1, 16, 64);
            se0 += __shfl_xor(se0, 32, 64);  se1 += __shfl_xor(se1, 32, 64);
            if (lane == 15) { redE[par][wv][0] = se0; redE[par][wv][1] = se1; }
        }

        // s-reduce over the wave's 16 cr-slots: bits 2-3 via DPP row_shr
        // (og-preserving; totals in lanes 12..15), bits 4-5 via swizzle.
        s0.x = dpp_add_shr4(s0.x);  s1.x = dpp_add_shr4(s1.x);
        s0.y = dpp_add_shr4(s0.y);  s1.y = dpp_add_shr4(s1.y);
        s0.z = dpp_add_shr4(s0.z);  s1.z = dpp_add_shr4(s1.z);
        s0.w = dpp_add_shr4(s0.w);  s1.w = dpp_add_shr4(s1.w);
        s0.x = dpp_add_shr8(s0.x);  s1.x = dpp_add_shr8(s1.x);
        s0.y = dpp_add_shr8(s0.y);  s1.y = dpp_add_shr8(s1.y);
        s0.z = dpp_add_shr8(s0.z);  s1.z = dpp_add_shr8(s1.z);
        s0.w = dpp_add_shr8(s0.w);  s1.w = dpp_add_shr8(s1.w);
        #pragma unroll
        for (int off = 16; off <= 32; off <<= 1) {
            s0.x += __shfl_xor(s0.x, off, 64);  s1.x += __shfl_xor(s1.x, off, 64);
            s0.y += __shfl_xor(s0.y, off, 64);  s1.y += __shfl_xor(s1.y, off, 64);
            s0.z += __shfl_xor(s0.z, off, 64);  s1.z += __shfl_xor(s1.z, off, 64);
            s0.w += __shfl_xor(s0.w, off, 64);  s1.w += __shfl_xor(s1.w, off, 64);
        }
        if (lane >= 12 && lane < 16) {   // lanes 12..15, og = lane&3
            *(float4*)&sRed[par][wv][0][(lane & 3) * 4] = s0;
            *(float4*)&sRed[par][wv][1][(lane & 3) * 4] = s1;
        }
        __syncthreads();

        // ---- all-wave redundant squash: every thread computes its own
        // og-quad of v for subs sA, sA+1 (no divergent phase, no vS).
        const float4 pa0 = *(const float4*)&sRed[par][sh * 2    ][0][og * 4];
        const float4 pb0 = *(const float4*)&sRed[par][sh * 2 + 1][0][og * 4];
        const float4 pa1 = *(const float4*)&sRed[par][sh * 2    ][1][og * 4];
        const float4 pb1 = *(const float4*)&sRed[par][sh * 2 + 1][1][og * 4];
        float inv0, inv1;
        if (it == 0) {
            inv0 = inv1 = 1.0f / (float)R_;
        } else {
            inv0 = 1.0f / (redE[par][sh * 2][0] + redE[par][sh * 2 + 1][0]);
            inv1 = 1.0f / (redE[par][sh * 2][1] + redE[par][sh * 2 + 1][1]);
        }
        float4 sc0, sc1;
        sc0.x = (pa0.x + pb0.x) * inv0;  sc1.x = (pa1.x + pb1.x) * inv1;
        sc0.y = (pa0.y + pb0.y) * inv0;  sc1.y = (pa1.y + pb1.y) * inv1;
        sc0.z = (pa0.z + pb0.z) * inv0;  sc1.z = (pa1.z + pb1.z) * inv1;
        sc0.w = (pa0.w + pb0.w) * inv0;  sc1.w = (pa1.w + pb1.w) * inv1;
        float sn0 = dot4(sc0, sc0);
        float sn1 = dot4(sc1, sc1);
        sn0 = dpp_add_xor1(sn0);  sn1 = dpp_add_xor1(sn1);   // sum over og quad
        sn0 = dpp_add_xor2(sn0);  sn1 = dpp_add_xor2(sn1);
        const float f0 = sqrtf(sn0) / (1.0f + sn0);
        const float f1 = sqrtf(sn1) / (1.0f + sn1);
        v0.x = sc0.x * f0;  v1.x = sc1.x * f1;
        v0.y = sc0.y * f0;  v1.y = sc1.y * f1;
        v0.z = sc0.z * f0;  v1.z = sc1.z * f1;
        v0.w = sc0.w * f0;  v1.w = sc1.w * f1;
        // No second barrier: next iter writes sRed/redE[!par], and the
        // par-buffer overwrite (it+2) sits behind it+1's barrier.
    }

    if (cr == 0) {   // 8 writer threads: (sh 0..1) x (og 0..3), 2 subs each
        *(float4*)&out[((((size_t)(b0 + sA)     * C_ + c) * W_ + p) * W_ + q) * COUT + og * 4] = v0;
        *(float4*)&out[((((size_t)(b0 + sA + 1) * C_ + c) * W_ + p) * W_ + q) * COUT + og * 4] = v1;
    }
}

extern "C" void kernel_launch(void* const* d_in, const int* in_sizes, int n_in,
                              void* d_out, int out_size, void* d_ws, size_t ws_size,
                              hipStream_t stream) {
    const float* x  = (const float*)d_in[0];
    const float* rw = (const float*)d_in[1];
    float* out = (float*)d_out;
    dim3 grid(W_ * W_, 2, C_);
    caps_routeC<<<grid, 256, 0, stream>>>(x, rw, out);
}